// Round 1
// baseline (904.644 us; speedup 1.0000x reference)
//
#include <hip/hip_runtime.h>
#include <cstdint>
#include <math.h>

#define DIMC 192
#define NTOK 256
#define HEADS 6
#define HD 32
#define NWIN 64

// ---------------- K1a: biasT[h][m][n] = table[rel[n][m]*6 + h] ----------------
__global__ void biasT_kernel(const float* __restrict__ table, const int* __restrict__ rel,
                             float* __restrict__ biasT) {
    int i = blockIdx.x * 256 + threadIdx.x;     // < 6*65536
    int h = i >> 16;
    int r = i & 65535;
    int m = r >> 8, n = r & 255;
    biasT[i] = table[rel[(n << 8) + m] * 6 + h];
}

// ---------------- K1b: maskT[w][m][n] = mask[w][n][m] ----------------
__global__ void maskT_kernel(const float* __restrict__ mask, float* __restrict__ maskT) {
    int i = blockIdx.x * 256 + threadIdx.x;     // < 64*65536
    int w = i >> 16;
    int r = i & 65535;
    int m = r >> 8, n = r & 255;
    maskT[i] = mask[(w << 16) + (n << 8) + m];
}

// ---------------- K2: QKV GEMM (65536x192 @ 192x576) with scatter ----------------
// Block tile 128x64, 128 threads, 8x8 micro-tile, KT=16.
#define BM 128
#define BN 64
#define KT 16

__launch_bounds__(128)
__global__ void qkv_gemm(const float* __restrict__ A, const float* __restrict__ W,
                         const float* __restrict__ bias,
                         float* __restrict__ q, float* __restrict__ k, float* __restrict__ v) {
    __shared__ float As[KT][BM + 4];   // +4 keeps rows 16B-aligned (132*4=528, 528%16==0)
    __shared__ float Bs[KT][BN];
    const int t = threadIdx.x;
    const int tx = t & 7;              // col group (8 cols)
    const int ty = t >> 3;             // row group (8 rows)
    const int m0 = blockIdx.x * BM;
    const int j0 = blockIdx.y * BN;
    float acc[8][8] = {};
    for (int k0 = 0; k0 < DIMC; k0 += KT) {
        #pragma unroll
        for (int i = 0; i < 4; ++i) {
            int c = t + 128 * i;       // 0..511 float4 chunks of A tile
            int row = c >> 2, kq = c & 3;
            float4 a4 = *(const float4*)(A + (size_t)(m0 + row) * DIMC + k0 + kq * 4);
            As[kq * 4 + 0][row] = a4.x;
            As[kq * 4 + 1][row] = a4.y;
            As[kq * 4 + 2][row] = a4.z;
            As[kq * 4 + 3][row] = a4.w;
        }
        #pragma unroll
        for (int i = 0; i < 2; ++i) {
            int c = t + 128 * i;       // 0..255 float4 chunks of B tile
            int kr = c >> 4, jq = c & 15;
            *(float4*)(&Bs[kr][jq * 4]) = *(const float4*)(W + (size_t)(k0 + kr) * 576 + j0 + jq * 4);
        }
        __syncthreads();
        #pragma unroll
        for (int kk = 0; kk < KT; ++kk) {
            float4 a0 = *(const float4*)(&As[kk][ty * 8]);
            float4 a1 = *(const float4*)(&As[kk][ty * 8 + 4]);
            float4 b0 = *(const float4*)(&Bs[kk][tx * 8]);
            float4 b1 = *(const float4*)(&Bs[kk][tx * 8 + 4]);
            float a[8] = {a0.x, a0.y, a0.z, a0.w, a1.x, a1.y, a1.z, a1.w};
            float b[8] = {b0.x, b0.y, b0.z, b0.w, b1.x, b1.y, b1.z, b1.w};
            #pragma unroll
            for (int i = 0; i < 8; ++i)
                #pragma unroll
                for (int j = 0; j < 8; ++j)
                    acc[i][j] += a[i] * b[j];
        }
        __syncthreads();
    }
    const float scale = 0.17677669529663687f;   // 1/sqrt(32), folded into q
    #pragma unroll
    for (int i = 0; i < 8; ++i) {
        int m = m0 + ty * 8 + i;
        int bb = m >> 8, n = m & 255;
        #pragma unroll
        for (int j = 0; j < 8; ++j) {
            int col = j0 + tx * 8 + j;
            int which = col / DIMC;
            int rem = col - which * DIMC;
            int h = rem >> 5, d = rem & 31;
            float val = acc[i][j] + bias[col];
            size_t off = (((size_t)bb * HEADS + h) * NTOK + n) * HD + d;
            if (which == 0)      q[off] = val * scale;
            else if (which == 1) k[off] = val;
            else                 v[off] = val;
        }
    }
}

// ---------------- K3: fused attention, one block per (b,h) ----------------
// 256 threads; lane owns one query row. K,V staged in exactly 64KB LDS.
// All K/V reads are wave-broadcast (same address) -> conflict-free.
__launch_bounds__(256)
__global__ void attn_kernel(const float* __restrict__ q, const float* __restrict__ kg,
                            const float* __restrict__ vg, const float* __restrict__ biasT,
                            const float* __restrict__ maskT, float* __restrict__ aout) {
    __shared__ float Ks[NTOK][HD];     // 32KB
    __shared__ float Vs[NTOK][HD];     // 32KB
    const int bh = blockIdx.x;         // b*6 + h
    const int b = bh / HEADS;
    const int h = bh - b * HEADS;
    const int w = b & 63;
    const int t = threadIdx.x;
    const size_t base = (size_t)bh * NTOK * HD;

    // stage K and V (coalesced float4 copies)
    #pragma unroll
    for (int i = 0; i < 8; ++i) {
        int f = t + 256 * i;           // float4 index, 2048 total
        *(float4*)(&Ks[0][0] + f * 4) = *(const float4*)(kg + base + f * 4);
        *(float4*)(&Vs[0][0] + f * 4) = *(const float4*)(vg + base + f * 4);
    }
    __syncthreads();

    const int n = t;                   // this lane's query row
    float qv[32];
    {
        const float* qr = q + base + n * HD;
        #pragma unroll
        for (int d4 = 0; d4 < 8; ++d4) {
            float4 f4 = *(const float4*)(qr + d4 * 4);
            qv[d4 * 4 + 0] = f4.x; qv[d4 * 4 + 1] = f4.y;
            qv[d4 * 4 + 2] = f4.z; qv[d4 * 4 + 3] = f4.w;
        }
    }
    const float* bptr = biasT + (size_t)h * 65536 + n;   // [h][m][n], coalesced in n
    const float* mptr = maskT + (size_t)w * 65536 + n;   // [w][m][n], coalesced in n

    float out[32] = {};
    float mx = -INFINITY, sum = 0.f;

    for (int c = 0; c < 16; ++c) {     // 16 chunks of 16 keys
        float s[16];
        #pragma unroll
        for (int mm = 0; mm < 16; ++mm) {
            int m = c * 16 + mm;
            float acc = bptr[m << 8] + mptr[m << 8];
            #pragma unroll
            for (int d4 = 0; d4 < 8; ++d4) {
                float4 k4 = *(const float4*)(&Ks[m][d4 * 4]);
                acc += qv[d4 * 4 + 0] * k4.x + qv[d4 * 4 + 1] * k4.y
                     + qv[d4 * 4 + 2] * k4.z + qv[d4 * 4 + 3] * k4.w;
            }
            s[mm] = acc;
        }
        float cmx = s[0];
        #pragma unroll
        for (int mm = 1; mm < 16; ++mm) cmx = fmaxf(cmx, s[mm]);
        float nmx = fmaxf(mx, cmx);
        float alpha = __expf(mx - nmx);
        sum *= alpha;
        #pragma unroll
        for (int d = 0; d < 32; ++d) out[d] *= alpha;
        #pragma unroll
        for (int mm = 0; mm < 16; ++mm) {
            int m = c * 16 + mm;
            float p = __expf(s[mm] - nmx);
            sum += p;
            #pragma unroll
            for (int d4 = 0; d4 < 8; ++d4) {
                float4 v4 = *(const float4*)(&Vs[m][d4 * 4]);
                out[d4 * 4 + 0] += p * v4.x; out[d4 * 4 + 1] += p * v4.y;
                out[d4 * 4 + 2] += p * v4.z; out[d4 * 4 + 3] += p * v4.w;
            }
        }
        mx = nmx;
    }

    float inv = 1.f / sum;
    float* orow = aout + ((size_t)b * NTOK + n) * DIMC + h * HD;   // (b, n, h*32+d)
    #pragma unroll
    for (int d4 = 0; d4 < 8; ++d4) {
        float4 o4 = {out[d4 * 4 + 0] * inv, out[d4 * 4 + 1] * inv,
                     out[d4 * 4 + 2] * inv, out[d4 * 4 + 3] * inv};
        *(float4*)(orow + d4 * 4) = o4;
    }
}

// ---------------- K4: proj GEMM (65536x192 @ 192x192) + bias ----------------
__launch_bounds__(128)
__global__ void proj_gemm(const float* __restrict__ A, const float* __restrict__ W,
                          const float* __restrict__ bias, float* __restrict__ out) {
    __shared__ float As[KT][BM + 4];
    __shared__ float Bs[KT][BN];
    const int t = threadIdx.x;
    const int tx = t & 7;
    const int ty = t >> 3;
    const int m0 = blockIdx.x * BM;
    const int j0 = blockIdx.y * BN;
    float acc[8][8] = {};
    for (int k0 = 0; k0 < DIMC; k0 += KT) {
        #pragma unroll
        for (int i = 0; i < 4; ++i) {
            int c = t + 128 * i;
            int row = c >> 2, kq = c & 3;
            float4 a4 = *(const float4*)(A + (size_t)(m0 + row) * DIMC + k0 + kq * 4);
            As[kq * 4 + 0][row] = a4.x;
            As[kq * 4 + 1][row] = a4.y;
            As[kq * 4 + 2][row] = a4.z;
            As[kq * 4 + 3][row] = a4.w;
        }
        #pragma unroll
        for (int i = 0; i < 2; ++i) {
            int c = t + 128 * i;
            int kr = c >> 4, jq = c & 15;
            *(float4*)(&Bs[kr][jq * 4]) = *(const float4*)(W + (size_t)(k0 + kr) * DIMC + j0 + jq * 4);
        }
        __syncthreads();
        #pragma unroll
        for (int kk = 0; kk < KT; ++kk) {
            float4 a0 = *(const float4*)(&As[kk][ty * 8]);
            float4 a1 = *(const float4*)(&As[kk][ty * 8 + 4]);
            float4 b0 = *(const float4*)(&Bs[kk][tx * 8]);
            float4 b1 = *(const float4*)(&Bs[kk][tx * 8 + 4]);
            float a[8] = {a0.x, a0.y, a0.z, a0.w, a1.x, a1.y, a1.z, a1.w};
            float b[8] = {b0.x, b0.y, b0.z, b0.w, b1.x, b1.y, b1.z, b1.w};
            #pragma unroll
            for (int i = 0; i < 8; ++i)
                #pragma unroll
                for (int j = 0; j < 8; ++j)
                    acc[i][j] += a[i] * b[j];
        }
        __syncthreads();
    }
    #pragma unroll
    for (int i = 0; i < 8; ++i) {
        int m = m0 + ty * 8 + i;
        int col = j0 + tx * 8;
        float4 r0 = {acc[i][0] + bias[col + 0], acc[i][1] + bias[col + 1],
                     acc[i][2] + bias[col + 2], acc[i][3] + bias[col + 3]};
        float4 r1 = {acc[i][4] + bias[col + 4], acc[i][5] + bias[col + 5],
                     acc[i][6] + bias[col + 6], acc[i][7] + bias[col + 7]};
        *(float4*)(out + (size_t)m * DIMC + col) = r0;
        *(float4*)(out + (size_t)m * DIMC + col + 4) = r1;
    }
}

extern "C" void kernel_launch(void* const* d_in, const int* in_sizes, int n_in,
                              void* d_out, int out_size, void* d_ws, size_t ws_size,
                              hipStream_t stream) {
    const float* x          = (const float*)d_in[0];   // (256,256,192)
    const float* mask       = (const float*)d_in[1];   // (64,256,256)
    const float* qkv_w      = (const float*)d_in[2];   // (192,576)
    const float* qkv_b      = (const float*)d_in[3];   // (576,)
    const float* proj_w     = (const float*)d_in[4];   // (192,192)
    const float* proj_b     = (const float*)d_in[5];   // (192,)
    const float* bias_table = (const float*)d_in[6];   // (1575,6)
    const int*   rel_index  = (const int*)d_in[7];     // (256,256)

    float* ws = (float*)d_ws;
    float* q     = ws;                       // 12,582,912 floats
    float* k     = ws + 12582912;            // 12,582,912
    float* v     = ws + 25165824;            // 12,582,912
    float* aout  = ws + 37748736;            // 12,582,912
    float* biasT = ws + 50331648;            //    393,216
    float* maskT = ws + 50724864;            //  4,194,304  -> total ~220MB

    biasT_kernel<<<1536, 256, 0, stream>>>(bias_table, rel_index, biasT);
    maskT_kernel<<<16384, 256, 0, stream>>>(mask, maskT);
    qkv_gemm<<<dim3(512, 9), 128, 0, stream>>>(x, qkv_w, qkv_b, q, k, v);
    attn_kernel<<<1536, 256, 0, stream>>>(q, k, v, biasT, maskT, aout);
    proj_gemm<<<dim3(512, 3), 128, 0, stream>>>(aout, proj_w, proj_b, (float*)d_out);
}

// Round 2
// 662.892 us; speedup vs baseline: 1.3647x; 1.3647x over previous
//
#include <hip/hip_runtime.h>
#include <cstdint>
#include <math.h>

#define DIMC 192
#define NTOK 256
#define HEADS 6
#define HD 32

typedef __bf16 bf16x8 __attribute__((ext_vector_type(8)));
typedef float f32x4 __attribute__((ext_vector_type(4)));

// ---------------- K1: biasT[h][q][k] = table[rel[q][k]*6 + h] ----------------
__global__ void biasT_kernel(const float* __restrict__ table, const int* __restrict__ rel,
                             float* __restrict__ biasT) {
    int i = blockIdx.x * 256 + threadIdx.x;     // < 6*65536
    int h = i >> 16;
    int r = i & 65535;                          // q*256 + k
    biasT[i] = table[rel[r] * 6 + h];
}

// ---------------- K2: QKV GEMM (65536x192 @ 192x576), bf16 q/k/vT out ----------------
#define BM 128
#define BN 64
#define KT 16

__launch_bounds__(128)
__global__ void qkv_gemm(const float* __restrict__ A, const float* __restrict__ W,
                         const float* __restrict__ bias,
                         __bf16* __restrict__ qout, __bf16* __restrict__ kout,
                         __bf16* __restrict__ vtout) {
    __shared__ float As[KT][BM + 4];
    __shared__ float Bs[KT][BN];
    const int t = threadIdx.x;
    const int tx = t & 7;
    const int ty = t >> 3;
    const int m0 = blockIdx.x * BM;
    const int j0 = blockIdx.y * BN;
    float acc[8][8] = {};
    for (int k0 = 0; k0 < DIMC; k0 += KT) {
        #pragma unroll
        for (int i = 0; i < 4; ++i) {
            int c = t + 128 * i;
            int row = c >> 2, kq = c & 3;
            float4 a4 = *(const float4*)(A + (size_t)(m0 + row) * DIMC + k0 + kq * 4);
            As[kq * 4 + 0][row] = a4.x;
            As[kq * 4 + 1][row] = a4.y;
            As[kq * 4 + 2][row] = a4.z;
            As[kq * 4 + 3][row] = a4.w;
        }
        #pragma unroll
        for (int i = 0; i < 2; ++i) {
            int c = t + 128 * i;
            int kr = c >> 4, jq = c & 15;
            *(float4*)(&Bs[kr][jq * 4]) = *(const float4*)(W + (size_t)(k0 + kr) * 576 + j0 + jq * 4);
        }
        __syncthreads();
        #pragma unroll
        for (int kk = 0; kk < KT; ++kk) {
            float4 a0 = *(const float4*)(&As[kk][ty * 8]);
            float4 a1 = *(const float4*)(&As[kk][ty * 8 + 4]);
            float4 b0 = *(const float4*)(&Bs[kk][tx * 8]);
            float4 b1 = *(const float4*)(&Bs[kk][tx * 8 + 4]);
            float a[8] = {a0.x, a0.y, a0.z, a0.w, a1.x, a1.y, a1.z, a1.w};
            float b[8] = {b0.x, b0.y, b0.z, b0.w, b1.x, b1.y, b1.z, b1.w};
            #pragma unroll
            for (int i = 0; i < 8; ++i)
                #pragma unroll
                for (int j = 0; j < 8; ++j)
                    acc[i][j] += a[i] * b[j];
        }
        __syncthreads();
    }
    const float scale = 0.17677669529663687f;   // 1/sqrt(32) folded into q
    const int col0 = j0 + tx * 8;
    const int which = col0 / DIMC;              // 8 cols never straddle a 192 boundary
    const int rem = col0 - which * DIMC;
    const int hh = rem >> 5, d0 = rem & 31;     // d0 multiple of 8
    #pragma unroll
    for (int i = 0; i < 8; ++i) {
        int m = m0 + ty * 8 + i;
        int bb = m >> 8, n = m & 255;
        size_t base = ((size_t)bb * HEADS + hh) * (NTOK * HD);
        if (which == 0) {
            bf16x8 tv;
            #pragma unroll
            for (int j = 0; j < 8; ++j)
                tv[j] = (__bf16)((acc[i][j] + bias[col0 + j]) * scale);
            *(bf16x8*)(qout + base + n * HD + d0) = tv;
        } else if (which == 1) {
            bf16x8 tv;
            #pragma unroll
            for (int j = 0; j < 8; ++j)
                tv[j] = (__bf16)(acc[i][j] + bias[col0 + j]);
            *(bf16x8*)(kout + base + n * HD + d0) = tv;
        } else {
            #pragma unroll
            for (int j = 0; j < 8; ++j)
                vtout[base + (size_t)(d0 + j) * NTOK + n] = (__bf16)(acc[i][j] + bias[col0 + j]);
        }
    }
}

// ---------------- K3: MFMA attention, one block (4 waves) per (b,h) ----------------
// Wave w owns query strip [w*64, w*64+64). K and V^T staged in LDS (bf16, padded).
// S = Q K^T via mfma_16x16x32_bf16, +bias+mask, exp (no max subtraction: scores O(1)),
// P -> per-wave-private LDS (C-layout -> A-layout), O += P V via MFMA. No barriers in loop.
__launch_bounds__(256)
__global__ void attn_mfma(const __bf16* __restrict__ qg, const __bf16* __restrict__ kg,
                          const __bf16* __restrict__ vtg, const float* __restrict__ biasg,
                          const float* __restrict__ maskg, float* __restrict__ aout) {
    __shared__ __bf16 Ks[NTOK][40];      // [key][dim], stride 40 (80B): 2-way max
    __shared__ __bf16 VTs[HD][264];      // [dim][key], stride 264 (528B): 2-way max
    __shared__ __bf16 Ps[4][64][40];     // per-wave [qrow][key-in-chunk], stride 40
    const int bh = blockIdx.x;
    const int b = bh / HEADS, h = bh - b * HEADS;
    const int w = b & 63;
    const int t = threadIdx.x;
    const size_t base = (size_t)bh * (NTOK * HD);

    // stage K: 1024 x 16B chunks
    #pragma unroll
    for (int it = 0; it < 4; ++it) {
        int c = t + 256 * it;
        int row = c >> 2, off = c & 3;
        *(uint4*)(&Ks[row][off * 8]) = *(const uint4*)(kg + base + row * HD + off * 8);
    }
    // stage V^T: 1024 x 16B chunks (32 rows x 512B)
    #pragma unroll
    for (int it = 0; it < 4; ++it) {
        int c = t + 256 * it;
        int row = c >> 5, off = c & 31;
        *(uint4*)(&VTs[row][off * 8]) = *(const uint4*)(vtg + base + row * NTOK + off * 8);
    }
    __syncthreads();

    const int wv = t >> 6, lane = t & 63;
    const int l16 = lane & 15, quad = lane >> 4;
    const int q0 = wv * 64;

    // Q A-frags for 4 query tiles (held in regs for whole kernel)
    bf16x8 qf[4];
    #pragma unroll
    for (int qt = 0; qt < 4; ++qt)
        qf[qt] = *(const bf16x8*)(qg + base + (size_t)(q0 + qt * 16 + l16) * HD + quad * 8);

    f32x4 o[4][2];
    #pragma unroll
    for (int qt = 0; qt < 4; ++qt)
        #pragma unroll
        for (int dt = 0; dt < 2; ++dt)
            o[qt][dt] = (f32x4){0.f, 0.f, 0.f, 0.f};
    float rsum[4][4] = {};

    const float* bias_h = biasg + (size_t)h * 65536;
    const float* mask_w = maskg + (size_t)w * 65536;

    for (int c = 0; c < 8; ++c) {        // 8 chunks of 32 keys
        const int kb = c * 32;
        bf16x8 kf[2];
        #pragma unroll
        for (int kt = 0; kt < 2; ++kt)
            kf[kt] = *(const bf16x8*)(&Ks[kb + kt * 16 + l16][quad * 8]);
        #pragma unroll
        for (int qt = 0; qt < 4; ++qt) {
            #pragma unroll
            for (int kt = 0; kt < 2; ++kt) {
                f32x4 s = (f32x4){0.f, 0.f, 0.f, 0.f};
                s = __builtin_amdgcn_mfma_f32_16x16x32_bf16(qf[qt], kf[kt], s, 0, 0, 0);
                const int key = kb + kt * 16 + l16;
                const float* bp = bias_h + key;
                const float* mp = mask_w + key;
                #pragma unroll
                for (int r = 0; r < 4; ++r) {
                    int qrow = q0 + qt * 16 + quad * 4 + r;
                    float sv = s[r] + bp[qrow * 256] + mp[qrow * 256];
                    float p = __expf(sv);
                    rsum[qt][r] += p;
                    Ps[wv][qt * 16 + quad * 4 + r][kt * 16 + l16] = (__bf16)p;
                }
            }
        }
        // PV: A-frag = P rows (same-wave LDS round-trip; compiler inserts lgkmcnt)
        bf16x8 vf[2];
        #pragma unroll
        for (int dt = 0; dt < 2; ++dt)
            vf[dt] = *(const bf16x8*)(&VTs[dt * 16 + l16][kb + quad * 8]);
        #pragma unroll
        for (int qt = 0; qt < 4; ++qt) {
            bf16x8 pf = *(const bf16x8*)(&Ps[wv][qt * 16 + l16][quad * 8]);
            #pragma unroll
            for (int dt = 0; dt < 2; ++dt)
                o[qt][dt] = __builtin_amdgcn_mfma_f32_16x16x32_bf16(pf, vf[dt], o[qt][dt], 0, 0, 0);
        }
    }

    // row sums: reduce across the 16 lanes sharing each quad-group (rows = quad*4+r)
    #pragma unroll
    for (int qt = 0; qt < 4; ++qt)
        #pragma unroll
        for (int r = 0; r < 4; ++r) {
            float s = rsum[qt][r];
            s += __shfl_xor(s, 1);
            s += __shfl_xor(s, 2);
            s += __shfl_xor(s, 4);
            s += __shfl_xor(s, 8);
            rsum[qt][r] = 1.f / s;
        }

    // write O: aout[b][qrow][h*32 + dim], coalesced in dim
    #pragma unroll
    for (int qt = 0; qt < 4; ++qt)
        #pragma unroll
        for (int dt = 0; dt < 2; ++dt)
            #pragma unroll
            for (int r = 0; r < 4; ++r) {
                int qrow = q0 + qt * 16 + quad * 4 + r;
                int dim = dt * 16 + l16;
                aout[((size_t)b * NTOK + qrow) * DIMC + h * HD + dim] = o[qt][dt][r] * rsum[qt][r];
            }
}

// ---------------- K4: proj GEMM (65536x192 @ 192x192) + bias ----------------
__launch_bounds__(128)
__global__ void proj_gemm(const float* __restrict__ A, const float* __restrict__ W,
                          const float* __restrict__ bias, float* __restrict__ out) {
    __shared__ float As[KT][BM + 4];
    __shared__ float Bs[KT][BN];
    const int t = threadIdx.x;
    const int tx = t & 7;
    const int ty = t >> 3;
    const int m0 = blockIdx.x * BM;
    const int j0 = blockIdx.y * BN;
    float acc[8][8] = {};
    for (int k0 = 0; k0 < DIMC; k0 += KT) {
        #pragma unroll
        for (int i = 0; i < 4; ++i) {
            int c = t + 128 * i;
            int row = c >> 2, kq = c & 3;
            float4 a4 = *(const float4*)(A + (size_t)(m0 + row) * DIMC + k0 + kq * 4);
            As[kq * 4 + 0][row] = a4.x;
            As[kq * 4 + 1][row] = a4.y;
            As[kq * 4 + 2][row] = a4.z;
            As[kq * 4 + 3][row] = a4.w;
        }
        #pragma unroll
        for (int i = 0; i < 2; ++i) {
            int c = t + 128 * i;
            int kr = c >> 4, jq = c & 15;
            *(float4*)(&Bs[kr][jq * 4]) = *(const float4*)(W + (size_t)(k0 + kr) * DIMC + j0 + jq * 4);
        }
        __syncthreads();
        #pragma unroll
        for (int kk = 0; kk < KT; ++kk) {
            float4 a0 = *(const float4*)(&As[kk][ty * 8]);
            float4 a1 = *(const float4*)(&As[kk][ty * 8 + 4]);
            float4 b0 = *(const float4*)(&Bs[kk][tx * 8]);
            float4 b1 = *(const float4*)(&Bs[kk][tx * 8 + 4]);
            float a[8] = {a0.x, a0.y, a0.z, a0.w, a1.x, a1.y, a1.z, a1.w};
            float b[8] = {b0.x, b0.y, b0.z, b0.w, b1.x, b1.y, b1.z, b1.w};
            #pragma unroll
            for (int i = 0; i < 8; ++i)
                #pragma unroll
                for (int j = 0; j < 8; ++j)
                    acc[i][j] += a[i] * b[j];
        }
        __syncthreads();
    }
    #pragma unroll
    for (int i = 0; i < 8; ++i) {
        int m = m0 + ty * 8 + i;
        int col = j0 + tx * 8;
        float4 r0 = {acc[i][0] + bias[col + 0], acc[i][1] + bias[col + 1],
                     acc[i][2] + bias[col + 2], acc[i][3] + bias[col + 3]};
        float4 r1 = {acc[i][4] + bias[col + 4], acc[i][5] + bias[col + 5],
                     acc[i][6] + bias[col + 6], acc[i][7] + bias[col + 7]};
        *(float4*)(out + (size_t)m * DIMC + col) = r0;
        *(float4*)(out + (size_t)m * DIMC + col + 4) = r1;
    }
}

extern "C" void kernel_launch(void* const* d_in, const int* in_sizes, int n_in,
                              void* d_out, int out_size, void* d_ws, size_t ws_size,
                              hipStream_t stream) {
    const float* x          = (const float*)d_in[0];   // (256,256,192)
    const float* mask       = (const float*)d_in[1];   // (64,256,256)
    const float* qkv_w      = (const float*)d_in[2];   // (192,576)
    const float* qkv_b      = (const float*)d_in[3];   // (576,)
    const float* proj_w     = (const float*)d_in[4];   // (192,192)
    const float* proj_b     = (const float*)d_in[5];   // (192,)
    const float* bias_table = (const float*)d_in[6];   // (1575,6)
    const int*   rel_index  = (const int*)d_in[7];     // (256,256)

    char* ws = (char*)d_ws;
    __bf16* q     = (__bf16*)(ws);                      // 12,582,912 bf16 = 25,165,824 B
    __bf16* k     = (__bf16*)(ws + 25165824);           // 25,165,824 B
    __bf16* vt    = (__bf16*)(ws + 50331648);           // 25,165,824 B
    float*  aout  = (float*)(ws + 75497472);            // 50,331,648 B
    float*  biasT = (float*)(ws + 125829120);           //  1,572,864 B  (~127 MB total)

    biasT_kernel<<<1536, 256, 0, stream>>>(bias_table, rel_index, biasT);
    qkv_gemm<<<dim3(512, 9), 128, 0, stream>>>(x, qkv_w, qkv_b, q, k, vt);
    attn_mfma<<<1536, 256, 0, stream>>>(q, k, vt, biasT, mask, aout);
    proj_gemm<<<dim3(512, 3), 128, 0, stream>>>(aout, proj_w, proj_b, (float*)d_out);
}

// Round 3
// 476.653 us; speedup vs baseline: 1.8979x; 1.3907x over previous
//
#include <hip/hip_runtime.h>
#include <cstdint>
#include <math.h>

#define DIMC 192
#define NTOK 256
#define HEADS 6
#define HD 32

typedef __bf16 bf16x8 __attribute__((ext_vector_type(8)));
typedef __bf16 bf16x4 __attribute__((ext_vector_type(4)));
typedef float f32x4 __attribute__((ext_vector_type(4)));

// ---------------- K1: biasT[h][q][k] = table[rel[q][k]*6 + h] ----------------
__global__ void biasT_kernel(const float* __restrict__ table, const int* __restrict__ rel,
                             float* __restrict__ biasT) {
    int i = blockIdx.x * 256 + threadIdx.x;     // < 6*65536
    int h = i >> 16;
    int r = i & 65535;                          // q*256 + k
    biasT[i] = table[rel[r] * 6 + h];
}

// ---------------- K2: QKV GEMM (65536x192 @ 192x576), bf16 q/k/vT out ----------------
#define BM 128
#define BN 64
#define KT 16

__launch_bounds__(128)
__global__ void qkv_gemm(const float* __restrict__ A, const float* __restrict__ W,
                         const float* __restrict__ bias,
                         __bf16* __restrict__ qout, __bf16* __restrict__ kout,
                         __bf16* __restrict__ vtout) {
    __shared__ float As[KT][BM + 4];
    __shared__ float Bs[KT][BN];
    const int t = threadIdx.x;
    const int tx = t & 7;
    const int ty = t >> 3;
    const int m0 = blockIdx.x * BM;
    const int j0 = blockIdx.y * BN;
    float acc[8][8] = {};
    for (int k0 = 0; k0 < DIMC; k0 += KT) {
        #pragma unroll
        for (int i = 0; i < 4; ++i) {
            int c = t + 128 * i;
            int row = c >> 2, kq = c & 3;
            float4 a4 = *(const float4*)(A + (size_t)(m0 + row) * DIMC + k0 + kq * 4);
            As[kq * 4 + 0][row] = a4.x;
            As[kq * 4 + 1][row] = a4.y;
            As[kq * 4 + 2][row] = a4.z;
            As[kq * 4 + 3][row] = a4.w;
        }
        #pragma unroll
        for (int i = 0; i < 2; ++i) {
            int c = t + 128 * i;
            int kr = c >> 4, jq = c & 15;
            *(float4*)(&Bs[kr][jq * 4]) = *(const float4*)(W + (size_t)(k0 + kr) * 576 + j0 + jq * 4);
        }
        __syncthreads();
        #pragma unroll
        for (int kk = 0; kk < KT; ++kk) {
            float4 a0 = *(const float4*)(&As[kk][ty * 8]);
            float4 a1 = *(const float4*)(&As[kk][ty * 8 + 4]);
            float4 b0 = *(const float4*)(&Bs[kk][tx * 8]);
            float4 b1 = *(const float4*)(&Bs[kk][tx * 8 + 4]);
            float a[8] = {a0.x, a0.y, a0.z, a0.w, a1.x, a1.y, a1.z, a1.w};
            float b[8] = {b0.x, b0.y, b0.z, b0.w, b1.x, b1.y, b1.z, b1.w};
            #pragma unroll
            for (int i = 0; i < 8; ++i)
                #pragma unroll
                for (int j = 0; j < 8; ++j)
                    acc[i][j] += a[i] * b[j];
        }
        __syncthreads();
    }
    const float scale = 0.17677669529663687f;   // 1/sqrt(32) folded into q
    const int col0 = j0 + tx * 8;
    const int which = col0 / DIMC;              // 8 cols never straddle a 192 boundary
    const int rem = col0 - which * DIMC;
    const int hh = rem >> 5, d0 = rem & 31;     // d0 multiple of 8
    #pragma unroll
    for (int i = 0; i < 8; ++i) {
        int m = m0 + ty * 8 + i;
        int bb = m >> 8, n = m & 255;
        size_t base = ((size_t)bb * HEADS + hh) * (NTOK * HD);
        if (which == 0) {
            bf16x8 tv;
            #pragma unroll
            for (int j = 0; j < 8; ++j)
                tv[j] = (__bf16)((acc[i][j] + bias[col0 + j]) * scale);
            *(bf16x8*)(qout + base + n * HD + d0) = tv;
        } else if (which == 1) {
            bf16x8 tv;
            #pragma unroll
            for (int j = 0; j < 8; ++j)
                tv[j] = (__bf16)(acc[i][j] + bias[col0 + j]);
            *(bf16x8*)(kout + base + n * HD + d0) = tv;
        } else {
            #pragma unroll
            for (int j = 0; j < 8; ++j)
                vtout[base + (size_t)(d0 + j) * NTOK + n] = (__bf16)(acc[i][j] + bias[col0 + j]);
        }
    }
}

// ---------------- K3: MFMA attention v2 (S^T orientation) ----------------
// One block (4 waves) per (b,h); wave owns 64-query strip. Computing S^T
// (mfma(kf,qf)) makes the C-layout row index the KEY, so bias/mask loads and
// P stores are consecutive-in-r: float4 global loads + ds_write_b64, instead
// of 64 scalar dwords + 32 ds_write_b16 per chunk.
__launch_bounds__(256, 3)
__global__ void attn_mfma(const __bf16* __restrict__ qg, const __bf16* __restrict__ kg,
                          const __bf16* __restrict__ vtg, const float* __restrict__ biasT,
                          const float* __restrict__ maskg, float* __restrict__ aout) {
    __shared__ __bf16 Ks[NTOK][40];      // [key][dim]   20480 B
    __shared__ __bf16 VTs[HD][264];      // [dim][key]   16896 B
    __shared__ __bf16 Ps[4][16][40];     // per-wave P buffer, reused per qt  5120 B
    __shared__ float  Sums[4][64];       // per-wave row sums               1024 B
    const int bh = blockIdx.x;
    const int b = bh / HEADS, h = bh - b * HEADS;
    const int w = b & 63;
    const int t = threadIdx.x;
    const size_t base = (size_t)bh * (NTOK * HD);

    // stage K: [key][dim], padded stride 40
    #pragma unroll
    for (int it = 0; it < 4; ++it) {
        int c = t + 256 * it;
        int row = c >> 2, off = c & 3;
        *(uint4*)(&Ks[row][off * 8]) = *(const uint4*)(kg + base + row * HD + off * 8);
    }
    // stage V^T: [dim][key], padded stride 264
    #pragma unroll
    for (int it = 0; it < 4; ++it) {
        int c = t + 256 * it;
        int row = c >> 5, off = c & 31;
        *(uint4*)(&VTs[row][off * 8]) = *(const uint4*)(vtg + base + row * NTOK + off * 8);
    }
    __syncthreads();

    const int wv = t >> 6, lane = t & 63;
    const int l16 = lane & 15, quad = lane >> 4;
    const int q0 = wv * 64;

    // Q fragments (held for whole kernel); same registers serve as B-operand of S^T
    bf16x8 qf[4];
    #pragma unroll
    for (int qt = 0; qt < 4; ++qt)
        qf[qt] = *(const bf16x8*)(qg + base + (size_t)(q0 + qt * 16 + l16) * HD + quad * 8);

    f32x4 o[4][2];
    #pragma unroll
    for (int qt = 0; qt < 4; ++qt)
        #pragma unroll
        for (int dt = 0; dt < 2; ++dt)
            o[qt][dt] = (f32x4){0.f, 0.f, 0.f, 0.f};
    float rsum[4] = {};

    // S^T tile: row=key=quad*4+r, col=qrow=l16 -> bias/mask vector along r
    const float* bias_q = biasT + (size_t)h * 65536 + (size_t)(q0 + l16) * 256 + quad * 4;
    const float* mask_q = maskg + (size_t)w * 65536 + (size_t)(q0 + l16) * 256 + quad * 4;

    for (int c = 0; c < 8; ++c) {
        const int kb = c * 32;
        // 16 float4 loads, issued up front, independent of the MFMAs below
        f32x4 bq[4][2], mq[4][2];
        #pragma unroll
        for (int qt = 0; qt < 4; ++qt)
            #pragma unroll
            for (int kt = 0; kt < 2; ++kt) {
                bq[qt][kt] = *(const f32x4*)(bias_q + qt * 4096 + kb + kt * 16);
                mq[qt][kt] = *(const f32x4*)(mask_q + qt * 4096 + kb + kt * 16);
            }
        bf16x8 kf[2];
        #pragma unroll
        for (int kt = 0; kt < 2; ++kt)
            kf[kt] = *(const bf16x8*)(&Ks[kb + kt * 16 + l16][quad * 8]);
        bf16x8 vf[2];
        #pragma unroll
        for (int dt = 0; dt < 2; ++dt)
            vf[dt] = *(const bf16x8*)(&VTs[dt * 16 + l16][kb + quad * 8]);

        #pragma unroll
        for (int qt = 0; qt < 4; ++qt) {
            #pragma unroll
            for (int kt = 0; kt < 2; ++kt) {
                f32x4 s = (f32x4){0.f, 0.f, 0.f, 0.f};
                s = __builtin_amdgcn_mfma_f32_16x16x32_bf16(kf[kt], qf[qt], s, 0, 0, 0);
                bf16x4 pk;
                #pragma unroll
                for (int r = 0; r < 4; ++r) {
                    float p = __expf(s[r] + bq[qt][kt][r] + mq[qt][kt][r]);
                    rsum[qt] += p;
                    pk[r] = (__bf16)p;
                }
                *(bf16x4*)(&Ps[wv][l16][kt * 16 + quad * 4]) = pk;  // ds_write_b64
            }
            // A-frag of P for PV (same-wave LDS round-trip, hw-ordered)
            bf16x8 pf = *(const bf16x8*)(&Ps[wv][l16][quad * 8]);
            #pragma unroll
            for (int dt = 0; dt < 2; ++dt)
                o[qt][dt] = __builtin_amdgcn_mfma_f32_16x16x32_bf16(pf, vf[dt], o[qt][dt], 0, 0, 0);
        }
    }

    // row sums: lane holds partial over its key subset for qrow=q0+qt*16+l16
    #pragma unroll
    for (int qt = 0; qt < 4; ++qt) {
        float s = rsum[qt];
        s += __shfl_xor(s, 16);
        s += __shfl_xor(s, 32);
        if (quad == 0) Sums[wv][qt * 16 + l16] = 1.0f / s;
    }
    // redistribute to O's C-layout rows (same wave; compiler inserts lgkmcnt)
    #pragma unroll
    for (int qt = 0; qt < 4; ++qt) {
        f32x4 inv = *(const f32x4*)(&Sums[wv][qt * 16 + quad * 4]);
        #pragma unroll
        for (int dt = 0; dt < 2; ++dt)
            #pragma unroll
            for (int r = 0; r < 4; ++r) {
                int qrow = q0 + qt * 16 + quad * 4 + r;
                aout[((size_t)b * NTOK + qrow) * DIMC + h * HD + dt * 16 + l16] = o[qt][dt][r] * inv[r];
            }
    }
}

// ---------------- K4: proj GEMM (65536x192 @ 192x192) + bias ----------------
__launch_bounds__(128)
__global__ void proj_gemm(const float* __restrict__ A, const float* __restrict__ W,
                          const float* __restrict__ bias, float* __restrict__ out) {
    __shared__ float As[KT][BM + 4];
    __shared__ float Bs[KT][BN];
    const int t = threadIdx.x;
    const int tx = t & 7;
    const int ty = t >> 3;
    const int m0 = blockIdx.x * BM;
    const int j0 = blockIdx.y * BN;
    float acc[8][8] = {};
    for (int k0 = 0; k0 < DIMC; k0 += KT) {
        #pragma unroll
        for (int i = 0; i < 4; ++i) {
            int c = t + 128 * i;
            int row = c >> 2, kq = c & 3;
            float4 a4 = *(const float4*)(A + (size_t)(m0 + row) * DIMC + k0 + kq * 4);
            As[kq * 4 + 0][row] = a4.x;
            As[kq * 4 + 1][row] = a4.y;
            As[kq * 4 + 2][row] = a4.z;
            As[kq * 4 + 3][row] = a4.w;
        }
        #pragma unroll
        for (int i = 0; i < 2; ++i) {
            int c = t + 128 * i;
            int kr = c >> 4, jq = c & 15;
            *(float4*)(&Bs[kr][jq * 4]) = *(const float4*)(W + (size_t)(k0 + kr) * DIMC + j0 + jq * 4);
        }
        __syncthreads();
        #pragma unroll
        for (int kk = 0; kk < KT; ++kk) {
            float4 a0 = *(const float4*)(&As[kk][ty * 8]);
            float4 a1 = *(const float4*)(&As[kk][ty * 8 + 4]);
            float4 b0 = *(const float4*)(&Bs[kk][tx * 8]);
            float4 b1 = *(const float4*)(&Bs[kk][tx * 8 + 4]);
            float a[8] = {a0.x, a0.y, a0.z, a0.w, a1.x, a1.y, a1.z, a1.w};
            float b[8] = {b0.x, b0.y, b0.z, b0.w, b1.x, b1.y, b1.z, b1.w};
            #pragma unroll
            for (int i = 0; i < 8; ++i)
                #pragma unroll
                for (int j = 0; j < 8; ++j)
                    acc[i][j] += a[i] * b[j];
        }
        __syncthreads();
    }
    #pragma unroll
    for (int i = 0; i < 8; ++i) {
        int m = m0 + ty * 8 + i;
        int col = j0 + tx * 8;
        float4 r0 = {acc[i][0] + bias[col + 0], acc[i][1] + bias[col + 1],
                     acc[i][2] + bias[col + 2], acc[i][3] + bias[col + 3]};
        float4 r1 = {acc[i][4] + bias[col + 4], acc[i][5] + bias[col + 5],
                     acc[i][6] + bias[col + 6], acc[i][7] + bias[col + 7]};
        *(float4*)(out + (size_t)m * DIMC + col) = r0;
        *(float4*)(out + (size_t)m * DIMC + col + 4) = r1;
    }
}

extern "C" void kernel_launch(void* const* d_in, const int* in_sizes, int n_in,
                              void* d_out, int out_size, void* d_ws, size_t ws_size,
                              hipStream_t stream) {
    const float* x          = (const float*)d_in[0];   // (256,256,192)
    const float* mask       = (const float*)d_in[1];   // (64,256,256)
    const float* qkv_w      = (const float*)d_in[2];   // (192,576)
    const float* qkv_b      = (const float*)d_in[3];   // (576,)
    const float* proj_w     = (const float*)d_in[4];   // (192,192)
    const float* proj_b     = (const float*)d_in[5];   // (192,)
    const float* bias_table = (const float*)d_in[6];   // (1575,6)
    const int*   rel_index  = (const int*)d_in[7];     // (256,256)

    char* ws = (char*)d_ws;
    __bf16* q     = (__bf16*)(ws);                      // 25,165,824 B
    __bf16* k     = (__bf16*)(ws + 25165824);           // 25,165,824 B
    __bf16* vt    = (__bf16*)(ws + 50331648);           // 25,165,824 B
    float*  aout  = (float*)(ws + 75497472);            // 50,331,648 B
    float*  biasT = (float*)(ws + 125829120);           //  1,572,864 B  (~127 MB total)

    biasT_kernel<<<1536, 256, 0, stream>>>(bias_table, rel_index, biasT);
    qkv_gemm<<<dim3(512, 9), 128, 0, stream>>>(x, qkv_w, qkv_b, q, k, vt);
    attn_mfma<<<1536, 256, 0, stream>>>(q, k, vt, biasT, mask, aout);
    proj_gemm<<<dim3(512, 3), 128, 0, stream>>>(aout, proj_w, proj_b, (float*)d_out);
}

// Round 4
// 281.268 us; speedup vs baseline: 3.2163x; 1.6947x over previous
//
#include <hip/hip_runtime.h>
#include <cstdint>
#include <math.h>

#define DIMC 192
#define NTOK 256
#define HEADS 6
#define HD 32

typedef __bf16 bf16x8 __attribute__((ext_vector_type(8)));
typedef __bf16 bf16x4 __attribute__((ext_vector_type(4)));
typedef float f32x4 __attribute__((ext_vector_type(4)));

__device__ __forceinline__ void gload_lds16(const __bf16* g, __bf16* l) {
    __builtin_amdgcn_global_load_lds((const __attribute__((address_space(1))) void*)g,
                                     (__attribute__((address_space(3))) void*)l, 16, 0, 0);
}

// ---------------- cast x (fp32) -> xb (bf16) ----------------
__global__ void cast_x(const float* __restrict__ x, __bf16* __restrict__ xb) {
    int i = blockIdx.x * 256 + threadIdx.x;         // one bf16x8 per thread
    float4 a = ((const float4*)x)[i * 2];
    float4 b = ((const float4*)x)[i * 2 + 1];
    bf16x8 o = {(__bf16)a.x, (__bf16)a.y, (__bf16)a.z, (__bf16)a.w,
                (__bf16)b.x, (__bf16)b.y, (__bf16)b.z, (__bf16)b.w};
    ((bf16x8*)xb)[i] = o;
}

// ---------------- transpose+cast weight: wt[n][k] = w[k][n] ----------------
__global__ void transcast(const float* __restrict__ w, __bf16* __restrict__ wt, int K, int N) {
    int i = blockIdx.x * 256 + threadIdx.x;         // i < N*K
    int n = i / K, k = i - n * K;
    wt[i] = (__bf16)w[(size_t)k * N + n];
}

// ---------------- biasT[h][q][k] = table[rel[q][k]*6 + h] ----------------
__global__ void biasT_kernel(const float* __restrict__ table, const int* __restrict__ rel,
                             float* __restrict__ biasT) {
    int i = blockIdx.x * 256 + threadIdx.x;
    int h = i >> 16;
    int r = i & 65535;
    biasT[i] = table[rel[r] * 6 + h];
}

// ---------------- QKV GEMM via MFMA: (65536x192)x(192x576) ----------------
// grid (6, 256): bx = 96-col block, by = 256-row block. 4 waves, wave = 64 rows x 96 cols.
// BK=64, XOR-swizzled 16B chunks in LDS (global_load_lds-compatible, conflict-light).
__launch_bounds__(256, 2)
__global__ void qkv_mfma(const __bf16* __restrict__ A, const __bf16* __restrict__ Wt,
                         const float* __restrict__ bias,
                         __bf16* __restrict__ qo, __bf16* __restrict__ ko, __bf16* __restrict__ vo) {
    __shared__ __bf16 As[256 * 64];    // 32KB
    __shared__ __bf16 Bs[96 * 64];     // 12KB
    const int t = threadIdx.x;
    const int wv = t >> 6, lane = t & 63;
    const int l16 = lane & 15, quad = lane >> 4;
    const int bx = blockIdx.x;
    const int m0 = blockIdx.y * 256;
    const int j0 = bx * 96;

    f32x4 acc[4][6];
    #pragma unroll
    for (int mt = 0; mt < 4; ++mt)
        #pragma unroll
        for (int nt = 0; nt < 6; ++nt)
            acc[mt][nt] = (f32x4){0.f, 0.f, 0.f, 0.f};

    for (int kit = 0; kit < 3; ++kit) {
        const int k0 = kit * 64;
        #pragma unroll
        for (int gi = 0; gi < 8; ++gi) {            // A: 2048 chunks, 32 groups
            int g = wv * 8 + gi;
            int cid = g * 64 + lane;
            int row = cid >> 3, kcs = cid & 7;
            int kcg = kcs ^ (row & 7);
            gload_lds16(A + (size_t)(m0 + row) * DIMC + k0 + kcg * 8, As + g * 512);
        }
        #pragma unroll
        for (int gi = 0; gi < 3; ++gi) {            // B: 768 chunks, 12 groups
            int g = wv * 3 + gi;
            int cid = g * 64 + lane;
            int n = cid >> 3, kcs = cid & 7;
            int kcg = kcs ^ (n & 7);
            gload_lds16(Wt + (size_t)(j0 + n) * DIMC + k0 + kcg * 8, Bs + g * 512);
        }
        __syncthreads();
        #pragma unroll
        for (int kk = 0; kk < 2; ++kk) {
            bf16x8 af[4], bfr[6];
            #pragma unroll
            for (int mt = 0; mt < 4; ++mt) {
                int row = wv * 64 + mt * 16 + l16;
                int ch = (kk * 4 + quad) ^ (row & 7);
                af[mt] = *(const bf16x8*)(As + row * 64 + ch * 8);
            }
            #pragma unroll
            for (int nt = 0; nt < 6; ++nt) {
                int n = nt * 16 + l16;
                int ch = (kk * 4 + quad) ^ (n & 7);
                bfr[nt] = *(const bf16x8*)(Bs + n * 64 + ch * 8);
            }
            #pragma unroll
            for (int mt = 0; mt < 4; ++mt)
                #pragma unroll
                for (int nt = 0; nt < 6; ++nt)
                    acc[mt][nt] = __builtin_amdgcn_mfma_f32_16x16x32_bf16(af[mt], bfr[nt], acc[mt][nt], 0, 0, 0);
        }
        __syncthreads();
    }

    // epilogue: re-tile via per-wave LDS, write bf16 [b,h,n,d] with 16B stores
    const int which = bx >> 1;                      // 0=q, 1=k, 2=v
    __bf16* outp = which == 0 ? qo : (which == 1 ? ko : vo);
    const float sc = which == 0 ? 0.17677669529663687f : 1.0f;
    float bq[6];
    #pragma unroll
    for (int nt = 0; nt < 6; ++nt) bq[nt] = bias[j0 + nt * 16 + l16];
    const int cloc = (bx & 1) * 96;                 // col within 192
    __bf16* tile = As + wv * 4096;                  // per-wave 8KB, [16][104]
    const int TP = 104;
    #pragma unroll
    for (int mt = 0; mt < 4; ++mt) {
        #pragma unroll
        for (int nt = 0; nt < 6; ++nt)
            #pragma unroll
            for (int r = 0; r < 4; ++r)
                tile[(quad * 4 + r) * TP + nt * 16 + l16] = (__bf16)((acc[mt][nt][r] + bq[nt]) * sc);
        int row = lane >> 2;
        #pragma unroll
        for (int it = 0; it < 3; ++it) {
            int c8 = (lane & 3) + it * 4;           // 12 16B-chunks per row
            bf16x8 val = *(const bf16x8*)(tile + row * TP + c8 * 8);
            int token = m0 + wv * 64 + mt * 16 + row;
            int b = token >> 8, n = token & 255;
            int cw = cloc + c8 * 8;
            int h = cw >> 5, d0 = cw & 31;
            *(bf16x8*)(outp + (((size_t)b * HEADS + h) * NTOK + n) * HD + d0) = val;
        }
    }
}

// ---------------- MFMA attention (S^T orientation), V transposed at staging ----------------
__launch_bounds__(256, 3)
__global__ void attn_mfma(const __bf16* __restrict__ qg, const __bf16* __restrict__ kg,
                          const __bf16* __restrict__ vg, const float* __restrict__ biasT,
                          const float* __restrict__ maskg, __bf16* __restrict__ aout) {
    __shared__ __bf16 Ks[NTOK][40];
    __shared__ __bf16 VTs[HD][264];
    __shared__ __bf16 Ps[4][16][40];
    __shared__ float  Sums[4][64];
    const int bh = blockIdx.x;
    const int b = bh / HEADS, h = bh - b * HEADS;
    const int w = b & 63;
    const int t = threadIdx.x;
    const size_t base = (size_t)bh * (NTOK * HD);

    #pragma unroll
    for (int it = 0; it < 4; ++it) {                // K: [key][dim]
        int c = t + 256 * it;
        int row = c >> 2, off = c & 3;
        *(uint4*)(&Ks[row][off * 8]) = *(const uint4*)(kg + base + row * HD + off * 8);
    }
    #pragma unroll
    for (int it = 0; it < 4; ++it) {                // V: transpose [n][d] -> [d][n]
        int d0 = it * 8;
        bf16x8 vv = *(const bf16x8*)(vg + base + t * HD + d0);
        #pragma unroll
        for (int j = 0; j < 8; ++j)
            VTs[d0 + j][t] = vv[j];                 // lanes consecutive n: conflict-free
    }
    __syncthreads();

    const int wv = t >> 6, lane = t & 63;
    const int l16 = lane & 15, quad = lane >> 4;
    const int q0 = wv * 64;

    bf16x8 qf[4];
    #pragma unroll
    for (int qt = 0; qt < 4; ++qt)
        qf[qt] = *(const bf16x8*)(qg + base + (size_t)(q0 + qt * 16 + l16) * HD + quad * 8);

    f32x4 o[4][2];
    #pragma unroll
    for (int qt = 0; qt < 4; ++qt)
        #pragma unroll
        for (int dt = 0; dt < 2; ++dt)
            o[qt][dt] = (f32x4){0.f, 0.f, 0.f, 0.f};
    float rsum[4] = {};

    const float* bias_q = biasT + (size_t)h * 65536 + (size_t)(q0 + l16) * 256 + quad * 4;
    const float* mask_q = maskg + (size_t)w * 65536 + (size_t)(q0 + l16) * 256 + quad * 4;

    for (int c = 0; c < 8; ++c) {
        const int kb = c * 32;
        f32x4 bq[4][2], mq[4][2];
        #pragma unroll
        for (int qt = 0; qt < 4; ++qt)
            #pragma unroll
            for (int kt = 0; kt < 2; ++kt) {
                bq[qt][kt] = *(const f32x4*)(bias_q + qt * 4096 + kb + kt * 16);
                mq[qt][kt] = *(const f32x4*)(mask_q + qt * 4096 + kb + kt * 16);
            }
        bf16x8 kf[2];
        #pragma unroll
        for (int kt = 0; kt < 2; ++kt)
            kf[kt] = *(const bf16x8*)(&Ks[kb + kt * 16 + l16][quad * 8]);
        bf16x8 vf[2];
        #pragma unroll
        for (int dt = 0; dt < 2; ++dt)
            vf[dt] = *(const bf16x8*)(&VTs[dt * 16 + l16][kb + quad * 8]);

        #pragma unroll
        for (int qt = 0; qt < 4; ++qt) {
            #pragma unroll
            for (int kt = 0; kt < 2; ++kt) {
                f32x4 s = (f32x4){0.f, 0.f, 0.f, 0.f};
                s = __builtin_amdgcn_mfma_f32_16x16x32_bf16(kf[kt], qf[qt], s, 0, 0, 0);
                bf16x4 pk;
                #pragma unroll
                for (int r = 0; r < 4; ++r) {
                    float p = __expf(s[r] + bq[qt][kt][r] + mq[qt][kt][r]);
                    rsum[qt] += p;
                    pk[r] = (__bf16)p;
                }
                *(bf16x4*)(&Ps[wv][l16][kt * 16 + quad * 4]) = pk;
            }
            bf16x8 pf = *(const bf16x8*)(&Ps[wv][l16][quad * 8]);
            #pragma unroll
            for (int dt = 0; dt < 2; ++dt)
                o[qt][dt] = __builtin_amdgcn_mfma_f32_16x16x32_bf16(pf, vf[dt], o[qt][dt], 0, 0, 0);
        }
    }

    #pragma unroll
    for (int qt = 0; qt < 4; ++qt) {
        float s = rsum[qt];
        s += __shfl_xor(s, 16);
        s += __shfl_xor(s, 32);
        if (quad == 0) Sums[wv][qt * 16 + l16] = 1.0f / s;
    }
    #pragma unroll
    for (int qt = 0; qt < 4; ++qt) {
        f32x4 inv = *(const f32x4*)(&Sums[wv][qt * 16 + quad * 4]);
        #pragma unroll
        for (int dt = 0; dt < 2; ++dt)
            #pragma unroll
            for (int r = 0; r < 4; ++r) {
                int qrow = q0 + qt * 16 + quad * 4 + r;
                aout[((size_t)b * NTOK + qrow) * DIMC + h * HD + dt * 16 + l16] =
                    (__bf16)(o[qt][dt][r] * inv[r]);
            }
    }
}

// ---------------- proj GEMM via MFMA: (65536x192)x(192x192) + bias, fp32 out ----------------
__launch_bounds__(256, 2)
__global__ void proj_mfma(const __bf16* __restrict__ A, const __bf16* __restrict__ Wt,
                          const float* __restrict__ bias, float* __restrict__ out) {
    __shared__ __bf16 As[256 * 64];
    __shared__ __bf16 Bs[96 * 64];
    const int t = threadIdx.x;
    const int wv = t >> 6, lane = t & 63;
    const int l16 = lane & 15, quad = lane >> 4;
    const int m0 = blockIdx.y * 256;
    const int j0 = blockIdx.x * 96;

    f32x4 acc[4][6];
    #pragma unroll
    for (int mt = 0; mt < 4; ++mt)
        #pragma unroll
        for (int nt = 0; nt < 6; ++nt)
            acc[mt][nt] = (f32x4){0.f, 0.f, 0.f, 0.f};

    for (int kit = 0; kit < 3; ++kit) {
        const int k0 = kit * 64;
        #pragma unroll
        for (int gi = 0; gi < 8; ++gi) {
            int g = wv * 8 + gi;
            int cid = g * 64 + lane;
            int row = cid >> 3, kcs = cid & 7;
            int kcg = kcs ^ (row & 7);
            gload_lds16(A + (size_t)(m0 + row) * DIMC + k0 + kcg * 8, As + g * 512);
        }
        #pragma unroll
        for (int gi = 0; gi < 3; ++gi) {
            int g = wv * 3 + gi;
            int cid = g * 64 + lane;
            int n = cid >> 3, kcs = cid & 7;
            int kcg = kcs ^ (n & 7);
            gload_lds16(Wt + (size_t)(j0 + n) * DIMC + k0 + kcg * 8, Bs + g * 512);
        }
        __syncthreads();
        #pragma unroll
        for (int kk = 0; kk < 2; ++kk) {
            bf16x8 af[4], bfr[6];
            #pragma unroll
            for (int mt = 0; mt < 4; ++mt) {
                int row = wv * 64 + mt * 16 + l16;
                int ch = (kk * 4 + quad) ^ (row & 7);
                af[mt] = *(const bf16x8*)(As + row * 64 + ch * 8);
            }
            #pragma unroll
            for (int nt = 0; nt < 6; ++nt) {
                int n = nt * 16 + l16;
                int ch = (kk * 4 + quad) ^ (n & 7);
                bfr[nt] = *(const bf16x8*)(Bs + n * 64 + ch * 8);
            }
            #pragma unroll
            for (int mt = 0; mt < 4; ++mt)
                #pragma unroll
                for (int nt = 0; nt < 6; ++nt)
                    acc[mt][nt] = __builtin_amdgcn_mfma_f32_16x16x32_bf16(af[mt], bfr[nt], acc[mt][nt], 0, 0, 0);
        }
        __syncthreads();
    }

    #pragma unroll
    for (int nt = 0; nt < 6; ++nt) {
        int colg = j0 + nt * 16 + l16;
        float bv = bias[colg];
        #pragma unroll
        for (int mt = 0; mt < 4; ++mt)
            #pragma unroll
            for (int r = 0; r < 4; ++r) {
                int token = m0 + wv * 64 + mt * 16 + quad * 4 + r;
                out[(size_t)token * DIMC + colg] = acc[mt][nt][r] + bv;
            }
    }
}

extern "C" void kernel_launch(void* const* d_in, const int* in_sizes, int n_in,
                              void* d_out, int out_size, void* d_ws, size_t ws_size,
                              hipStream_t stream) {
    const float* x          = (const float*)d_in[0];
    const float* mask       = (const float*)d_in[1];
    const float* qkv_w      = (const float*)d_in[2];
    const float* qkv_b      = (const float*)d_in[3];
    const float* proj_w     = (const float*)d_in[4];
    const float* proj_b     = (const float*)d_in[5];
    const float* bias_table = (const float*)d_in[6];
    const int*   rel_index  = (const int*)d_in[7];

    char* ws = (char*)d_ws;
    __bf16* xb    = (__bf16*)(ws);                  // 25,165,824 B (reused as aoutb)
    __bf16* q     = (__bf16*)(ws + 25165824);
    __bf16* k     = (__bf16*)(ws + 50331648);
    __bf16* v     = (__bf16*)(ws + 75497472);
    float*  biasT = (float*)(ws + 100663296);       // 1,572,864 B
    __bf16* wqt   = (__bf16*)(ws + 102236160);      // 221,184 B
    __bf16* wpt   = (__bf16*)(ws + 102457344);      // 73,728 B -> total ~102.5 MB
    __bf16* aoutb = xb;                             // xb dead after qkv_mfma

    cast_x<<<6144, 256, 0, stream>>>(x, xb);
    transcast<<<432, 256, 0, stream>>>(qkv_w, wqt, DIMC, 576);
    transcast<<<144, 256, 0, stream>>>(proj_w, wpt, DIMC, DIMC);
    biasT_kernel<<<1536, 256, 0, stream>>>(bias_table, rel_index, biasT);
    qkv_mfma<<<dim3(6, 256), 256, 0, stream>>>(xb, wqt, qkv_b, q, k, v);
    attn_mfma<<<1536, 256, 0, stream>>>(q, k, v, biasT, mask, aoutb);
    proj_mfma<<<dim3(2, 256), 256, 0, stream>>>(aoutb, wpt, proj_b, (float*)d_out);
}